// Round 8
// baseline (393.107 us; speedup 1.0000x reference)
//
#include <hip/hip_runtime.h>
#include <stdint.h>

// DuelingQNet fused, bf16 MFMA 16x16x32. v8: NO LDS ring. Weights are 643KB,
// permanently L2/L1-resident (every CU streams the same pages) -> each wave
// loads B-fragments directly global->VGPR (dwordx4), no DMA, no counted
// vmcnt, no per-chunk barriers. Waves free-run; only TWO __syncthreads in
// the whole kernel (pre-stage visibility; zbuf->pall overlay WAR). LDS keeps
// just xbw/pall/plast/vbuf/bmL = 53760 B -> 3 blocks/CU. Per-wave compute
// structure identical to v6 (peeled layers, 88 VGPR, no spills).

typedef __attribute__((ext_vector_type(8))) short short8;  // bf16x8 frag (4 VGPR)
typedef __attribute__((ext_vector_type(4))) float f32x4;   // MFMA C/D frag
typedef __attribute__((ext_vector_type(2))) float f32x2;

__device__ __forceinline__ unsigned short f2bf(float f) {
  union { float f; uint32_t u; } v; v.f = f;
  uint32_t r = v.u + 0x7FFFu + ((v.u >> 16) & 1u);  // RNE
  return (unsigned short)(r >> 16);
}
__device__ __forceinline__ float blo(uint32_t w) { union { uint32_t u; float f; } c; c.u = w << 16; return c.f; }
__device__ __forceinline__ float bhi(uint32_t w) { union { uint32_t u; float f; } c; c.u = w & 0xffff0000u; return c.f; }
__device__ __forceinline__ float b2f(unsigned short h) { union { uint32_t u; float f; } c; c.u = ((uint32_t)h) << 16; return c.f; }
__device__ __forceinline__ uint32_t cvtpk(float lo, float hi) {
  uint32_t d;
  asm("v_cvt_pk_bf16_f32 %0, %1, %2" : "=v"(d) : "v"(lo), "v"(hi));
  return d;
}
__device__ __forceinline__ f32x2 unpk2(uint32_t w) {
  f32x2 r; r.x = blo(w); r.y = bhi(w); return r;
}
union S8 { short8 s; uint32_t u[4]; };

// ---- prep: fp32 weights -> bf16 q-major fragment pages (UNCHANGED) ----
// page (4096 us) = [4 q][128 n][8 kk], k = st*32 + q*8 + kk. page k = ws + k*4096.
// WbF pg 0..7 | WgF pg 8..9 ([st][q][64 n][8]) | WmF pg 10..73 | Wa1F pg 74..77
// | Wa2F pg 78 ([st][q][16 n][8], 2048 us valid)
__global__ void prep_weights(const float* __restrict__ Wb, const float* __restrict__ Wm,
                             const float* __restrict__ Wa1, const float* __restrict__ Wg,
                             const float* __restrict__ Wgl, const float* __restrict__ Wa2,
                             unsigned short* __restrict__ ws) {
  int idx = blockIdx.x * 256 + threadIdx.x;
  if (idx >= 321536) return;
  unsigned short v;
  if (idx < 32768) {
    int st = idx >> 12, q = (idx >> 10) & 3, n = (idx >> 3) & 127, kk = idx & 7;
    v = f2bf(Wb[(st * 32 + q * 8 + kk) * 128 + n]);
  } else if (idx < 40960) {
    int t = idx - 32768; int st = t >> 11, q = (t >> 9) & 3, n = (t >> 3) & 63, kk = t & 7;
    int k = st * 32 + q * 8 + kk;
    if (n < 48)      v = f2bf(Wg[(n >> 4) * 2048 + k * 16 + (n & 15)]);
    else if (n < 52) v = f2bf(Wgl[k * 4 + (n - 48)]);
    else             v = 0;
  } else if (idx < 303104) {
    int t = idx - 40960; int pg = t >> 12; int lj = pg >> 2, st = pg & 3;
    int q = (t >> 10) & 3, n = (t >> 3) & 127, kk = t & 7;
    v = f2bf(Wm[lj * 16384 + (st * 32 + q * 8 + kk) * 128 + n]);
  } else if (idx < 319488) {
    int t = idx - 303104; int st = t >> 12, q = (t >> 10) & 3, n = (t >> 3) & 127, kk = t & 7;
    v = f2bf(Wa1[(st * 32 + q * 8 + kk) * 128 + n]);
  } else {
    int t = idx - 319488; int st = t >> 9, q = (t >> 7) & 3, n = (t >> 3) & 15, kk = t & 7;
    int k = st * 32 + q * 8 + kk;
    v = (n < 8) ? f2bf(Wa2[k * 8 + n]) : (unsigned short)0;
  }
  ws[idx] = v;
}

// one 16-row x 128-col x K=32 slice, B-fragments straight from GLOBAL (L1/L2-hot)
__device__ __forceinline__ void gemmG(const short8 xst, const unsigned short* __restrict__ C,
                                      int q, int ml, f32x4 a[8]) {
#pragma unroll
  for (int nt = 0; nt < 8; ++nt) {
    short8 bf = *(const short8*)(C + q * 1024 + (nt * 16 + ml) * 8);
    a[nt] = __builtin_amdgcn_mfma_f32_16x16x32_bf16(xst, bf, a[nt], 0, 0, 0);
  }
}
// 4 A-frags from a [16][136] LDS tile
__device__ __forceinline__ void ldx4(const unsigned short* xbw, int q, int ml, short8 f[4]) {
#pragma unroll
  for (int st = 0; st < 4; ++st) f[st] = *(const short8*)(xbw + ml * 136 + st * 32 + q * 8);
}

// xin_j = sum_i p[i][j] * xo_i for all j, packed bf16x2 math in f32x2
__device__ __forceinline__ void combine_layer(const short8 xo[4][4],
                                              const unsigned short* __restrict__ prow,
                                              short8 xin[4][4]) {
  float p[4][4];
#pragma unroll
  for (int j = 0; j < 4; ++j) {
    uint32_t pw0 = *(const uint32_t*)(prow + j * 4);
    uint32_t pw1 = *(const uint32_t*)(prow + j * 4 + 2);
    p[j][0] = blo(pw0); p[j][1] = bhi(pw0); p[j][2] = blo(pw1); p[j][3] = bhi(pw1);
  }
#pragma unroll
  for (int st = 0; st < 4; ++st) {
    S8 x0, x1, x2, x3;
    x0.s = xo[0][st]; x1.s = xo[1][st]; x2.s = xo[2][st]; x3.s = xo[3][st];
    S8 r0, r1, r2, r3;
#pragma unroll
    for (int w = 0; w < 4; ++w) {
      f32x2 u0 = unpk2(x0.u[w]), u1 = unpk2(x1.u[w]), u2 = unpk2(x2.u[w]), u3 = unpk2(x3.u[w]);
      f32x2 s0 = p[0][0] * u0 + p[0][1] * u1 + p[0][2] * u2 + p[0][3] * u3;
      f32x2 s1 = p[1][0] * u0 + p[1][1] * u1 + p[1][2] * u2 + p[1][3] * u3;
      f32x2 s2 = p[2][0] * u0 + p[2][1] * u1 + p[2][2] * u2 + p[2][3] * u3;
      f32x2 s3 = p[3][0] * u0 + p[3][1] * u1 + p[3][2] * u2 + p[3][3] * u3;
      r0.u[w] = cvtpk(s0.x, s0.y); r1.u[w] = cvtpk(s1.x, s1.y);
      r2.u[w] = cvtpk(s2.x, s2.y); r3.u[w] = cvtpk(s3.x, s3.y);
    }
    xin[0][st] = r0.s; xin[1][st] = r1.s; xin[2][st] = r2.s; xin[3][st] = r3.s;
  }
}

__global__ __attribute__((amdgpu_flat_work_group_size(512, 512), amdgpu_waves_per_eu(2)))
void dueling_fused(
    const float* __restrict__ o, const float* __restrict__ zmap, const float* __restrict__ coll,
    const float* __restrict__ bb, const float* __restrict__ Wz, const float* __restrict__ bz,
    const float* __restrict__ bm, const float* __restrict__ Wv, const float* __restrict__ bv,
    const float* __restrict__ ba1, const float* __restrict__ ba2,
    const unsigned short* __restrict__ ws, float* __restrict__ out)
{
  // LDS 53760 B: xbuf 34816 @0 (8 waves x [16][136] bf16)
  //              pall 12288 @34816 ([3][128][16] bf16; zbufF overlays, dead before)
  //              plast 2048 @47104 ([128][4] f32, wave-private rows)
  //              vbuf 512 @49152 ([128] f32, wave-private rows; NOT overlaid:
  //                               no lockstep barriers to order overlay reuse)
  //              bmL 4096 @49664 ([16][128] bf16 module biases)
  __shared__ __align__(16) unsigned char smem[53760];
  unsigned short* xbuf  = (unsigned short*)(smem);
  unsigned short* pall  = (unsigned short*)(smem + 34816);
  float*          zbufF = (float*)(smem + 34816);
  float*          plast = (float*)(smem + 47104);
  float*          vbuf  = (float*)(smem + 49152);
  unsigned short* bmL   = (unsigned short*)(smem + 49664);

  const int tid = threadIdx.x;
  const int wv  = tid >> 6;        // 0..7
  const int lane = tid & 63;
  const int q   = lane >> 4;
  const int ml  = lane & 15;
  const int row0 = blockIdx.x * 128;
  unsigned short* xbw = xbuf + wv * 2176;   // wave-private [16][136]

  // ---- pre-stage (cross-wave LDS: zbuf, bmL) ----
  for (int i = tid; i < 1280; i += 512) {
    if (i < 1152) { int r = i / 9, c = i - r * 9; zbufF[r * 12 + c] = zmap[(row0 + r) * 9 + c]; }
    else          { int r = i - 1152; zbufF[r * 12 + 9] = coll[row0 + r]; }
  }
  for (int i = tid; i < 2048; i += 512) bmL[i] = f2bf(bm[i]);

  short8 of[8];  // full o row as A-frags (row = ml, k = st*32 + q*8 ..)
  const float* orow = o + (size_t)(row0 + wv * 16 + ml) * 256;
#pragma unroll
  for (int st = 0; st < 8; ++st) {
    float4 v0 = *(const float4*)(orow + st * 32 + q * 8);
    float4 v1 = *(const float4*)(orow + st * 32 + q * 8 + 4);
    S8 af;
    af.u[0] = cvtpk(v0.x, v0.y); af.u[1] = cvtpk(v0.z, v0.w);
    af.u[2] = cvtpk(v1.x, v1.y); af.u[3] = cvtpk(v1.z, v1.w);
    of[st] = af.s;
  }
  __syncthreads();   // zbuf + bmL visible to all waves

  const f32x4 z4 = {0.f, 0.f, 0.f, 0.f};

  // ---- Phase 1: f0 = relu(o @ Wb + bb), pages 0..7 ----
  f32x4 acc[8];
#pragma unroll
  for (int nt = 0; nt < 8; ++nt) acc[nt] = z4;
#pragma unroll
  for (int st = 0; st < 8; ++st) gemmG(of[st], ws + st * 4096, q, ml, acc);
#pragma unroll
  for (int nt = 0; nt < 8; ++nt) {
    float bbv = bb[nt * 16 + ml];
#pragma unroll
    for (int r2 = 0; r2 < 4; ++r2) {
      float v = fmaxf(acc[nt][r2] + bbv, 0.f);
      acc[nt][r2] = v;
      xbw[(q * 4 + r2) * 136 + nt * 16 + ml] = f2bf(v);
    }
  }
  short8 f0f[4];
  ldx4(xbw, q, ml, f0f);

  // ---- Phase 2: g = relu(z @ Wz + bz) * f0 -> xbw ----
#pragma unroll
  for (int nt = 0; nt < 8; ++nt) {
    int col = nt * 16 + ml;
    float wz[10];
#pragma unroll
    for (int k = 0; k < 10; ++k) wz[k] = Wz[k * 128 + col];
    float bzv = bz[col];
#pragma unroll
    for (int r2 = 0; r2 < 4; ++r2) {
      int row = wv * 16 + q * 4 + r2;
      float zd = bzv;
#pragma unroll
      for (int k = 0; k < 10; ++k) zd += zbufF[row * 12 + k] * wz[k];
      xbw[(q * 4 + r2) * 136 + col] = f2bf(fmaxf(zd, 0.f) * acc[nt][r2]);
    }
  }
  short8 gf[4];
  ldx4(xbw, q, ml, gf);
  __syncthreads();   // all zbuf reads done -> pall may overwrite the region

  // ---- Phase 3: routing logits (N=64), pages 8..9 ----
  f32x4 ag[4];
#pragma unroll
  for (int nt = 0; nt < 4; ++nt) ag[nt] = z4;
  {
    const unsigned short* C8 = ws + 8 * 4096;
    const unsigned short* C9 = ws + 9 * 4096;
#pragma unroll
    for (int sp = 0; sp < 2; ++sp)
#pragma unroll
      for (int nt = 0; nt < 4; ++nt) {
        short8 bf = *(const short8*)(C8 + sp * 2048 + q * 512 + (nt * 16 + ml) * 8);
        ag[nt] = __builtin_amdgcn_mfma_f32_16x16x32_bf16(gf[sp], bf, ag[nt], 0, 0, 0);
      }
#pragma unroll
    for (int sp = 0; sp < 2; ++sp)
#pragma unroll
      for (int nt = 0; nt < 4; ++nt) {
        short8 bf = *(const short8*)(C9 + sp * 2048 + q * 512 + (nt * 16 + ml) * 8);
        ag[nt] = __builtin_amdgcn_mfma_f32_16x16x32_bf16(gf[2 + sp], bf, ag[nt], 0, 0, 0);
      }
  }
#pragma unroll
  for (int li = 0; li < 3; ++li) {      // softmax over i (lane bits 2..3); col = i*4+j
#pragma unroll
    for (int r2 = 0; r2 < 4; ++r2) {
      float a = ag[li][r2];
      float m = fmaxf(a, __shfl_xor(a, 4)); m = fmaxf(m, __shfl_xor(m, 8));
      float e = __expf(a - m);
      float s = e; s += __shfl_xor(s, 4); s += __shfl_xor(s, 8);
      pall[(li * 128 + wv * 16 + q * 4 + r2) * 16 + (ml & 3) * 4 + (ml >> 2)] = f2bf(e / s);
    }
  }
#pragma unroll
  for (int r2 = 0; r2 < 4; ++r2) {      // p_last: softmax over m = ml<4
    float a = ag[3][r2];
    float m = fmaxf(a, __shfl_xor(a, 1)); m = fmaxf(m, __shfl_xor(m, 2));
    float e = __expf(a - m);
    float s = e; s += __shfl_xor(s, 1); s += __shfl_xor(s, 2);
    if (ml < 4) plast[(wv * 16 + q * 4 + r2) * 4 + ml] = e / s;
  }
  // pall/plast rows are wave-private (rows wv*16..+15) -> no barrier needed.

  // ---- Layer 0 (peeled): pages 10..25 ----
  short8 xo[4][4];
  f32x4 a[8];
#pragma unroll
  for (int j = 0; j < 4; ++j) {
    if (j > 0) ldx4(xbw, q, ml, xo[j - 1]);
#pragma unroll
    for (int nt = 0; nt < 8; ++nt) a[nt] = z4;
#pragma unroll
    for (int st = 0; st < 4; ++st) gemmG(f0f[st], ws + (10 + j * 4 + st) * 4096, q, ml, a);
#pragma unroll
    for (int nt = 0; nt < 8; ++nt) {
      float bmv = b2f(bmL[j * 128 + nt * 16 + ml]);
#pragma unroll
      for (int r2 = 0; r2 < 4; ++r2)
        xbw[(q * 4 + r2) * 136 + nt * 16 + ml] = f2bf(fmaxf(a[nt][r2] + bmv, 0.f));
    }
  }

  // ---- Layers 1..2: pages 26..57 ----
  short8 xin[4][4];
  for (int l = 1; l <= 2; ++l) {
    ldx4(xbw, q, ml, xo[3]);
    combine_layer(xo, pall + ((l - 1) * 128 + wv * 16 + ml) * 16, xin);
#pragma unroll
    for (int j = 0; j < 4; ++j) {
      if (j > 0) ldx4(xbw, q, ml, xo[j - 1]);
#pragma unroll
      for (int nt = 0; nt < 8; ++nt) a[nt] = z4;
#pragma unroll
      for (int st = 0; st < 4; ++st)
        gemmG(xin[j][st], ws + (10 + (l * 4 + j) * 4 + st) * 4096, q, ml, a);
#pragma unroll
      for (int nt = 0; nt < 8; ++nt) {
        float bmv = b2f(bmL[(l * 4 + j) * 128 + nt * 16 + ml]);
#pragma unroll
        for (int r2 = 0; r2 < 4; ++r2)
          xbw[(q * 4 + r2) * 136 + nt * 16 + ml] = f2bf(fmaxf(a[nt][r2] + bmv, 0.f));
      }
    }
  }

  // ---- Layer 3 (peeled): pages 58..73; feature = sum_j p_last[j]*relu(...) ----
  f32x4 feat[8];
  {
    ldx4(xbw, q, ml, xo[3]);
    combine_layer(xo, pall + (2 * 128 + wv * 16 + ml) * 16, xin);
#pragma unroll
    for (int nt = 0; nt < 8; ++nt) feat[nt] = z4;
#pragma unroll
    for (int j = 0; j < 4; ++j) {
#pragma unroll
      for (int nt = 0; nt < 8; ++nt) a[nt] = z4;
#pragma unroll
      for (int st = 0; st < 4; ++st)
        gemmG(xin[j][st], ws + (58 + j * 4 + st) * 4096, q, ml, a);
      float pl[4];
#pragma unroll
      for (int r2 = 0; r2 < 4; ++r2) pl[r2] = plast[(wv * 16 + q * 4 + r2) * 4 + j];
#pragma unroll
      for (int nt = 0; nt < 8; ++nt) {
        float bmv = b2f(bmL[(12 + j) * 128 + nt * 16 + ml]);
#pragma unroll
        for (int r2 = 0; r2 < 4; ++r2)
          feat[nt][r2] += pl[r2] * fmaxf(a[nt][r2] + bmv, 0.f);
      }
    }
  }

  // ---- Heads: a1 gemm pages 74..77, Wa2 page 78 ----
#pragma unroll
  for (int nt = 0; nt < 8; ++nt)
#pragma unroll
    for (int r2 = 0; r2 < 4; ++r2)
      xbw[(q * 4 + r2) * 136 + nt * 16 + ml] = f2bf(feat[nt][r2]);
  short8 ff[4];
  ldx4(xbw, q, ml, ff);
#pragma unroll
  for (int nt = 0; nt < 8; ++nt) a[nt] = z4;
#pragma unroll
  for (int st = 0; st < 4; ++st) gemmG(ff[st], ws + (74 + st) * 4096, q, ml, a);

  // value head: feat . Wv + bv  (vbuf rows are wave-private)
  {
    float wvv[8];
#pragma unroll
    for (int nt = 0; nt < 8; ++nt) wvv[nt] = Wv[nt * 16 + ml];
    float bvv = bv[0];
#pragma unroll
    for (int r2 = 0; r2 < 4; ++r2) {
      float v = 0.f;
#pragma unroll
      for (int nt = 0; nt < 8; ++nt) v += feat[nt][r2] * wvv[nt];
      v += __shfl_xor(v, 1); v += __shfl_xor(v, 2); v += __shfl_xor(v, 4); v += __shfl_xor(v, 8);
      if (ml == 0) vbuf[wv * 16 + q * 4 + r2] = v + bvv;
    }
  }

  // a1 = relu(feat @ Wa1 + ba1)
#pragma unroll
  for (int nt = 0; nt < 8; ++nt) {
    float b1v = ba1[nt * 16 + ml];
#pragma unroll
    for (int r2 = 0; r2 < 4; ++r2)
      xbw[(q * 4 + r2) * 136 + nt * 16 + ml] = f2bf(fmaxf(a[nt][r2] + b1v, 0.f));
  }
  short8 a1f[4];
  ldx4(xbw, q, ml, a1f);

  // adv = a1 @ Wa2 + ba2; out = adv - mean(adv) + value
  const unsigned short* C78 = ws + 78 * 4096;
  f32x4 av = z4;
#pragma unroll
  for (int st = 0; st < 4; ++st) {
    short8 bf = *(const short8*)(C78 + st * 512 + q * 128 + ml * 8);
    av = __builtin_amdgcn_mfma_f32_16x16x32_bf16(a1f[st], bf, av, 0, 0, 0);
  }
  float ba2v = ba2[ml & 7];
#pragma unroll
  for (int r2 = 0; r2 < 4; ++r2) {
    float aa = av[r2] + ba2v;
    float s = aa + __shfl_xor(aa, 1); s += __shfl_xor(s, 2); s += __shfl_xor(s, 4);
    if (ml < 8)
      out[(size_t)(row0 + wv * 16 + q * 4 + r2) * 8 + ml] = aa - s * 0.125f + vbuf[wv * 16 + q * 4 + r2];
  }
}

extern "C" void kernel_launch(void* const* d_in, const int* in_sizes, int n_in,
                              void* d_out, int out_size, void* d_ws, size_t ws_size,
                              hipStream_t stream) {
  const float* o   = (const float*)d_in[0];
  const float* zm  = (const float*)d_in[1];
  const float* cp  = (const float*)d_in[2];
  const float* Wb  = (const float*)d_in[3];
  const float* bb  = (const float*)d_in[4];
  const float* Wz  = (const float*)d_in[5];
  const float* bz  = (const float*)d_in[6];
  const float* Wm  = (const float*)d_in[7];
  const float* bm  = (const float*)d_in[8];
  const float* Wg  = (const float*)d_in[9];
  const float* Wgl = (const float*)d_in[10];
  const float* Wv  = (const float*)d_in[11];
  const float* bv  = (const float*)d_in[12];
  const float* Wa1 = (const float*)d_in[13];
  const float* ba1 = (const float*)d_in[14];
  const float* Wa2 = (const float*)d_in[15];
  const float* ba2 = (const float*)d_in[16];
  unsigned short* wsT = (unsigned short*)d_ws;

  int B = in_sizes[0] / 256;  // 65536

  hipLaunchKernelGGL(prep_weights, dim3(1256), dim3(256), 0, stream,
                     Wb, Wm, Wa1, Wg, Wgl, Wa2, wsT);
  hipLaunchKernelGGL(dueling_fused, dim3(B / 128), dim3(512), 0, stream,
                     o, zm, cp, bb, Wz, bz, bm, Wv, bv, ba1, ba2,
                     wsT, (float*)d_out);
}

// Round 9
// 215.456 us; speedup vs baseline: 1.8245x; 1.8245x over previous
//
#include <hip/hip_runtime.h>
#include <stdint.h>

// DuelingQNet fused, bf16 MFMA 16x16x32. v9 == v6 with ONE change:
// amdgpu_waves_per_eu(2) -> (4). Evidence: measured occupancy tracks this
// attribute (v4:(4)->38%, v6/v8:(2)->22%) not the LDS arithmetic; at ~1
// resident block/CU the per-chunk DMA latency is exposed at all 79 barriers
// (the 128us invariant). VGPR=88 <= 128 so (4) costs nothing. Everything
// else byte-identical to v6: 128 rows/block, 512 thr, 8 waves, 79 x 8KB ring,
// 3 slots, vmcnt(1)+lgkmcnt(0)+s_barrier, q-major pages, no spills.

typedef __attribute__((ext_vector_type(8))) short short8;  // bf16x8 frag (4 VGPR)
typedef __attribute__((ext_vector_type(4))) float f32x4;   // MFMA C/D frag
typedef __attribute__((ext_vector_type(2))) float f32x2;
typedef __attribute__((address_space(1))) const unsigned int u32_g;
typedef __attribute__((address_space(3))) unsigned int u32_l;

__device__ __forceinline__ unsigned short f2bf(float f) {
  union { float f; uint32_t u; } v; v.f = f;
  uint32_t r = v.u + 0x7FFFu + ((v.u >> 16) & 1u);  // RNE
  return (unsigned short)(r >> 16);
}
__device__ __forceinline__ float blo(uint32_t w) { union { uint32_t u; float f; } c; c.u = w << 16; return c.f; }
__device__ __forceinline__ float bhi(uint32_t w) { union { uint32_t u; float f; } c; c.u = w & 0xffff0000u; return c.f; }
__device__ __forceinline__ float b2f(unsigned short h) { union { uint32_t u; float f; } c; c.u = ((uint32_t)h) << 16; return c.f; }
__device__ __forceinline__ uint32_t cvtpk(float lo, float hi) {
  uint32_t d;
  asm("v_cvt_pk_bf16_f32 %0, %1, %2" : "=v"(d) : "v"(lo), "v"(hi));
  return d;
}
__device__ __forceinline__ f32x2 unpk2(uint32_t w) {
  f32x2 r; r.x = blo(w); r.y = bhi(w); return r;
}
union S8 { short8 s; uint32_t u[4]; };

// ---- prep: fp32 weights -> bf16 q-major fragment pages, STREAM-ORDERED ws ----
// page (4096 us) = [4 q][128 n][8 kk], k = st*32 + q*8 + kk.
// ushort offsets: WbF 8pg@0 | WgF [4 st][4 q][64 n][8]@32768 | WmF 64pg@40960
//                 Wa1F 4pg@303104 | Wa2F [4 st][4 q][16 n][8]@319488
__global__ void prep_weights(const float* __restrict__ Wb, const float* __restrict__ Wm,
                             const float* __restrict__ Wa1, const float* __restrict__ Wg,
                             const float* __restrict__ Wgl, const float* __restrict__ Wa2,
                             unsigned short* __restrict__ ws) {
  int idx = blockIdx.x * 256 + threadIdx.x;
  if (idx >= 321536) return;
  unsigned short v;
  if (idx < 32768) {
    int st = idx >> 12, q = (idx >> 10) & 3, n = (idx >> 3) & 127, kk = idx & 7;
    v = f2bf(Wb[(st * 32 + q * 8 + kk) * 128 + n]);
  } else if (idx < 40960) {
    int t = idx - 32768; int st = t >> 11, q = (t >> 9) & 3, n = (t >> 3) & 63, kk = t & 7;
    int k = st * 32 + q * 8 + kk;
    if (n < 48)      v = f2bf(Wg[(n >> 4) * 2048 + k * 16 + (n & 15)]);
    else if (n < 52) v = f2bf(Wgl[k * 4 + (n - 48)]);
    else             v = 0;
  } else if (idx < 303104) {
    int t = idx - 40960; int pg = t >> 12; int lj = pg >> 2, st = pg & 3;
    int q = (t >> 10) & 3, n = (t >> 3) & 127, kk = t & 7;
    v = f2bf(Wm[lj * 16384 + (st * 32 + q * 8 + kk) * 128 + n]);
  } else if (idx < 319488) {
    int t = idx - 303104; int st = t >> 12, q = (t >> 10) & 3, n = (t >> 3) & 127, kk = t & 7;
    v = f2bf(Wa1[(st * 32 + q * 8 + kk) * 128 + n]);
  } else {
    int t = idx - 319488; int st = t >> 9, q = (t >> 7) & 3, n = (t >> 3) & 15, kk = t & 7;
    int k = st * 32 + q * 8 + kk;
    v = (n < 8) ? f2bf(Wa2[k * 8 + n]) : (unsigned short)0;
  }
  ws[idx] = v;
}

__device__ __forceinline__ void gld16(const void* g, void* l) {
  __builtin_amdgcn_global_load_lds((u32_g*)g, (u32_l*)l, 16, 0, 0);
}

// one 16-row x 128-col x K=32 slice from a q-major 8KB ring chunk
__device__ __forceinline__ void gemm32(const short8 xst, const unsigned short* C,
                                       int q, int ml, f32x4 a[8]) {
#pragma unroll
  for (int nt = 0; nt < 8; ++nt) {
    short8 bf = *(const short8*)(C + q * 1024 + (nt * 16 + ml) * 8);
    a[nt] = __builtin_amdgcn_mfma_f32_16x16x32_bf16(xst, bf, a[nt], 0, 0, 0);
  }
}
// 4 A-frags from a [16][136] tile
__device__ __forceinline__ void ldx4(const unsigned short* xbw, int q, int ml, short8 f[4]) {
#pragma unroll
  for (int st = 0; st < 4; ++st) f[st] = *(const short8*)(xbw + ml * 136 + st * 32 + q * 8);
}

// xin_j = sum_i p[i][j] * xo_i for all j, packed bf16x2 math in f32x2
__device__ __forceinline__ void combine_layer(const short8 xo[4][4],
                                              const unsigned short* __restrict__ prow,
                                              short8 xin[4][4]) {
  float p[4][4];
#pragma unroll
  for (int j = 0; j < 4; ++j) {
    uint32_t pw0 = *(const uint32_t*)(prow + j * 4);
    uint32_t pw1 = *(const uint32_t*)(prow + j * 4 + 2);
    p[j][0] = blo(pw0); p[j][1] = bhi(pw0); p[j][2] = blo(pw1); p[j][3] = bhi(pw1);
  }
#pragma unroll
  for (int st = 0; st < 4; ++st) {
    S8 x0, x1, x2, x3;
    x0.s = xo[0][st]; x1.s = xo[1][st]; x2.s = xo[2][st]; x3.s = xo[3][st];
    S8 r0, r1, r2, r3;
#pragma unroll
    for (int w = 0; w < 4; ++w) {
      f32x2 u0 = unpk2(x0.u[w]), u1 = unpk2(x1.u[w]), u2 = unpk2(x2.u[w]), u3 = unpk2(x3.u[w]);
      f32x2 s0 = p[0][0] * u0 + p[0][1] * u1 + p[0][2] * u2 + p[0][3] * u3;
      f32x2 s1 = p[1][0] * u0 + p[1][1] * u1 + p[1][2] * u2 + p[1][3] * u3;
      f32x2 s2 = p[2][0] * u0 + p[2][1] * u1 + p[2][2] * u2 + p[2][3] * u3;
      f32x2 s3 = p[3][0] * u0 + p[3][1] * u1 + p[3][2] * u2 + p[3][3] * u3;
      r0.u[w] = cvtpk(s0.x, s0.y); r1.u[w] = cvtpk(s1.x, s1.y);
      r2.u[w] = cvtpk(s2.x, s2.y); r3.u[w] = cvtpk(s3.x, s3.y);
    }
    xin[0][st] = r0.s; xin[1][st] = r1.s; xin[2][st] = r2.s; xin[3][st] = r3.s;
  }
}

// ring sync (v4-proven): counted vmcnt(1) keeps 1 chunk (1 load/lane at 512
// thr) in flight across the barrier; lgkmcnt(0) guards the WAR on slot reuse.
#define RSYNC1() asm volatile("s_waitcnt vmcnt(1) lgkmcnt(0)\n\ts_barrier" ::: "memory")
#define RSYNC0() asm volatile("s_waitcnt vmcnt(0) lgkmcnt(0)\n\ts_barrier" ::: "memory")
#define RSTEP1(PTR) do { RSYNC1(); ring_issue(); (PTR) = ring_next(); } while (0)
#define RSTEP0(PTR) do { RSYNC0(); ring_issue(); (PTR) = ring_next(); } while (0)

__global__ __attribute__((amdgpu_flat_work_group_size(512, 512), amdgpu_waves_per_eu(4)))
void dueling_fused(
    const float* __restrict__ o, const float* __restrict__ zmap, const float* __restrict__ coll,
    const float* __restrict__ bb, const float* __restrict__ Wz, const float* __restrict__ bz,
    const float* __restrict__ bm, const float* __restrict__ Wv, const float* __restrict__ bv,
    const float* __restrict__ ba1, const float* __restrict__ ba2,
    const unsigned short* __restrict__ ws, float* __restrict__ out)
{
  // LDS 77824 B: ring 3x8192 @0 | xbuf 34816 @24576 (8 waves x [16][136] bf16)
  //              pall 12288 @59392 (zbufF ovl) | plast 2048 @71680 (vbuf ovl)
  //              bmL 4096 @73728
  __shared__ __align__(16) unsigned char smem[77824];
  unsigned short* xbuf  = (unsigned short*)(smem + 24576);
  unsigned short* pall  = (unsigned short*)(smem + 59392);   // [3][128][16] bf16 (wave-private rows)
  float*          zbufF = (float*)(smem + 59392);            // [128][12] (dead before pall)
  float*          plast = (float*)(smem + 71680);            // [128][4]  (wave-private rows)
  float*          vbuf  = (float*)(smem + 71680);            // [128]     (after plast dead)
  unsigned short* bmL   = (unsigned short*)(smem + 73728);   // [16][128] bf16 module biases

  const int tid = threadIdx.x;
  const int wv  = tid >> 6;        // 0..7
  const int lane = tid & 63;
  const int q   = lane >> 4;
  const int ml  = lane & 15;
  const int row0 = blockIdx.x * 128;
  unsigned short* xbw = xbuf + wv * 2176;   // wave-private [16][136]

  // ---- pre-ring staging (ALL stray VMEM drained before ring starts) ----
  for (int i = tid; i < 1280; i += 512) {
    if (i < 1152) { int r = i / 9, c = i - r * 9; zbufF[r * 12 + c] = zmap[(row0 + r) * 9 + c]; }
    else          { int r = i - 1152; zbufF[r * 12 + 9] = coll[row0 + r]; }
  }
  for (int i = tid; i < 2048; i += 512) bmL[i] = f2bf(bm[i]);

  short8 of[8];  // full o row as A-frags (row = ml, k = st*32 + q*8 ..)
  const float* orow = o + (size_t)(row0 + wv * 16 + ml) * 256;
#pragma unroll
  for (int st = 0; st < 8; ++st) {
    float4 v0 = *(const float4*)(orow + st * 32 + q * 8);
    float4 v1 = *(const float4*)(orow + st * 32 + q * 8 + 4);
    S8 af;
    af.u[0] = cvtpk(v0.x, v0.y); af.u[1] = cvtpk(v0.z, v0.w);
    af.u[2] = cvtpk(v1.x, v1.y); af.u[3] = cvtpk(v1.z, v1.w);
    of[st] = af.s;
  }
  asm volatile("s_waitcnt vmcnt(0) lgkmcnt(0)" ::: "memory");

  // ---- ring state (wave-uniform scalars) ----
  int r_kiss = 0, r_riss = 0, r_rc = 0;
  const char* r_gsrc = (const char*)ws;
  const int wld  = wv << 10;            // wave's 1KB of each 8KB chunk
  const int ln16 = (tid & 63) << 4;
  auto ring_issue = [&]() {
    if (r_kiss <= 78) {
      char* l = (char*)smem + r_riss;
      // chunk 78 has only 4KB valid: upper-half waves re-read the lower 4KB.
      int soff = (r_kiss == 78) ? (wld & 4095) : wld;
      gld16(r_gsrc + soff + ln16, l + wld + ln16);
      r_gsrc += 8192;
    }
    ++r_kiss;
    r_riss += 8192; if (r_riss == 24576) r_riss = 0;
  };
  auto ring_next = [&]() -> const unsigned short* {
    const unsigned short* p = (const unsigned short*)(smem + r_rc);
    r_rc += 8192; if (r_rc == 24576) r_rc = 0;
    return p;
  };
  ring_issue(); ring_issue();   // chunks 0,1 in flight

  const f32x4 z4 = {0.f, 0.f, 0.f, 0.f};
  const unsigned short* C;

  // ---- Phase 1: f0 = relu(o @ Wb + bb), chunks 0..7 ----
  f32x4 acc[8];
#pragma unroll
  for (int nt = 0; nt < 8; ++nt) acc[nt] = z4;
#pragma unroll
  for (int st = 0; st < 8; ++st) { RSTEP1(C); gemm32(of[st], C, q, ml, acc); }
  // f0 epilogue: bias+relu; keep fp32 in acc (for g), bf16 copy in xbw
#pragma unroll
  for (int nt = 0; nt < 8; ++nt) {
    float bbv = bb[nt * 16 + ml];   // stray VMEM -> drained at RSTEP0 below
#pragma unroll
    for (int r2 = 0; r2 < 4; ++r2) {
      float v = fmaxf(acc[nt][r2] + bbv, 0.f);
      acc[nt][r2] = v;
      xbw[(q * 4 + r2) * 136 + nt * 16 + ml] = f2bf(v);
    }
  }
  short8 f0f[4];
  ldx4(xbw, q, ml, f0f);

  // ---- Phase 2: g = relu(z @ Wz + bz) * f0 -> xbw (Wz direct from global/L1) ----
#pragma unroll
  for (int nt = 0; nt < 8; ++nt) {
    int col = nt * 16 + ml;
    float wz[10];
#pragma unroll
    for (int k = 0; k < 10; ++k) wz[k] = Wz[k * 128 + col];   // strays, drained below
    float bzv = bz[col];
#pragma unroll
    for (int r2 = 0; r2 < 4; ++r2) {
      int row = wv * 16 + q * 4 + r2;
      float zd = bzv;
#pragma unroll
      for (int k = 0; k < 10; ++k) zd += zbufF[row * 12 + k] * wz[k];
      xbw[(q * 4 + r2) * 136 + col] = f2bf(fmaxf(zd, 0.f) * acc[nt][r2]);
    }
  }
  short8 gf[4];
  ldx4(xbw, q, ml, gf);

  // ---- Phase 3: routing logits (N=64), chunk 8 (st0,1; drains strays) + 9 ----
  f32x4 ag[4];
#pragma unroll
  for (int nt = 0; nt < 4; ++nt) ag[nt] = z4;
  RSTEP0(C);
#pragma unroll
  for (int sp = 0; sp < 2; ++sp)
#pragma unroll
    for (int nt = 0; nt < 4; ++nt) {
      short8 bf = *(const short8*)(C + sp * 2048 + q * 512 + (nt * 16 + ml) * 8);
      ag[nt] = __builtin_amdgcn_mfma_f32_16x16x32_bf16(gf[sp], bf, ag[nt], 0, 0, 0);
    }
  RSTEP1(C);
#pragma unroll
  for (int sp = 0; sp < 2; ++sp)
#pragma unroll
    for (int nt = 0; nt < 4; ++nt) {
      short8 bf = *(const short8*)(C + sp * 2048 + q * 512 + (nt * 16 + ml) * 8);
      ag[nt] = __builtin_amdgcn_mfma_f32_16x16x32_bf16(gf[2 + sp], bf, ag[nt], 0, 0, 0);
    }
#pragma unroll
  for (int li = 0; li < 3; ++li) {      // softmax over i (lane bits 2..3); col = i*4+j
#pragma unroll
    for (int r2 = 0; r2 < 4; ++r2) {
      float a = ag[li][r2];
      float m = fmaxf(a, __shfl_xor(a, 4)); m = fmaxf(m, __shfl_xor(m, 8));
      float e = __expf(a - m);
      float s = e; s += __shfl_xor(s, 4); s += __shfl_xor(s, 8);
      pall[(li * 128 + wv * 16 + q * 4 + r2) * 16 + (ml & 3) * 4 + (ml >> 2)] = f2bf(e / s);
    }
  }
#pragma unroll
  for (int r2 = 0; r2 < 4; ++r2) {      // p_last: softmax over m = ml<4
    float a = ag[3][r2];
    float m = fmaxf(a, __shfl_xor(a, 1)); m = fmaxf(m, __shfl_xor(m, 2));
    float e = __expf(a - m);
    float s = e; s += __shfl_xor(s, 1); s += __shfl_xor(s, 2);
    if (ml < 4) plast[(wv * 16 + q * 4 + r2) * 4 + ml] = e / s;
  }

  // ---- Layer 0 (peeled): chunks 10..25; bias from bmL (no VMEM in loop) ----
  short8 xo[4][4];
  f32x4 a[8];
#pragma unroll
  for (int j = 0; j < 4; ++j) {
    if (j > 0) ldx4(xbw, q, ml, xo[j - 1]);
#pragma unroll
    for (int nt = 0; nt < 8; ++nt) a[nt] = z4;
#pragma unroll
    for (int st = 0; st < 4; ++st) { RSTEP1(C); gemm32(f0f[st], C, q, ml, a); }
#pragma unroll
    for (int nt = 0; nt < 8; ++nt) {
      float bmv = b2f(bmL[j * 128 + nt * 16 + ml]);
#pragma unroll
      for (int r2 = 0; r2 < 4; ++r2)
        xbw[(q * 4 + r2) * 136 + nt * 16 + ml] = f2bf(fmaxf(a[nt][r2] + bmv, 0.f));
    }
  }

  // ---- Layers 1..2: chunks 26..57 ----
  short8 xin[4][4];
  for (int l = 1; l <= 2; ++l) {
    ldx4(xbw, q, ml, xo[3]);
    combine_layer(xo, pall + ((l - 1) * 128 + wv * 16 + ml) * 16, xin);
#pragma unroll
    for (int j = 0; j < 4; ++j) {
      if (j > 0) ldx4(xbw, q, ml, xo[j - 1]);
#pragma unroll
      for (int nt = 0; nt < 8; ++nt) a[nt] = z4;
#pragma unroll
      for (int st = 0; st < 4; ++st) { RSTEP1(C); gemm32(xin[j][st], C, q, ml, a); }
#pragma unroll
      for (int nt = 0; nt < 8; ++nt) {
        float bmv = b2f(bmL[(l * 4 + j) * 128 + nt * 16 + ml]);
#pragma unroll
        for (int r2 = 0; r2 < 4; ++r2)
          xbw[(q * 4 + r2) * 136 + nt * 16 + ml] = f2bf(fmaxf(a[nt][r2] + bmv, 0.f));
      }
    }
  }

  // ---- Layer 3 (peeled): chunks 58..73; feature = sum_j p_last[j]*relu(...) ----
  f32x4 feat[8];
  {
    ldx4(xbw, q, ml, xo[3]);
    combine_layer(xo, pall + (2 * 128 + wv * 16 + ml) * 16, xin);
#pragma unroll
    for (int nt = 0; nt < 8; ++nt) feat[nt] = z4;
#pragma unroll
    for (int j = 0; j < 4; ++j) {
#pragma unroll
      for (int nt = 0; nt < 8; ++nt) a[nt] = z4;
#pragma unroll
      for (int st = 0; st < 4; ++st) { RSTEP1(C); gemm32(xin[j][st], C, q, ml, a); }
      float pl[4];
#pragma unroll
      for (int r2 = 0; r2 < 4; ++r2) pl[r2] = plast[(wv * 16 + q * 4 + r2) * 4 + j];
#pragma unroll
      for (int nt = 0; nt < 8; ++nt) {
        float bmv = b2f(bmL[(12 + j) * 128 + nt * 16 + ml]);
#pragma unroll
        for (int r2 = 0; r2 < 4; ++r2)
          feat[nt][r2] += pl[r2] * fmaxf(a[nt][r2] + bmv, 0.f);
      }
    }
  }

  // ---- Heads: a1 gemm chunks 74..77, Wa2 chunk 78 (RSTEP0 drains head strays) ----
#pragma unroll
  for (int nt = 0; nt < 8; ++nt)
#pragma unroll
    for (int r2 = 0; r2 < 4; ++r2)
      xbw[(q * 4 + r2) * 136 + nt * 16 + ml] = f2bf(feat[nt][r2]);
  short8 ff[4];
  ldx4(xbw, q, ml, ff);
#pragma unroll
  for (int nt = 0; nt < 8; ++nt) a[nt] = z4;
#pragma unroll
  for (int st = 0; st < 4; ++st) { RSTEP1(C); gemm32(ff[st], C, q, ml, a); }

  // value head: feat . Wv + bv (Wv from global; strays drained at RSTEP0 below)
  {
    float wvv[8];
#pragma unroll
    for (int nt = 0; nt < 8; ++nt) wvv[nt] = Wv[nt * 16 + ml];
    float bvv = bv[0];
#pragma unroll
    for (int r2 = 0; r2 < 4; ++r2) {
      float v = 0.f;
#pragma unroll
      for (int nt = 0; nt < 8; ++nt) v += feat[nt][r2] * wvv[nt];
      v += __shfl_xor(v, 1); v += __shfl_xor(v, 2); v += __shfl_xor(v, 4); v += __shfl_xor(v, 8);
      if (ml == 0) vbuf[wv * 16 + q * 4 + r2] = v + bvv;
    }
  }

  // a1 = relu(feat @ Wa1 + ba1)
#pragma unroll
  for (int nt = 0; nt < 8; ++nt) {
    float b1v = ba1[nt * 16 + ml];
#pragma unroll
    for (int r2 = 0; r2 < 4; ++r2)
      xbw[(q * 4 + r2) * 136 + nt * 16 + ml] = f2bf(fmaxf(a[nt][r2] + b1v, 0.f));
  }
  short8 a1f[4];
  ldx4(xbw, q, ml, a1f);

  RSTEP0(C);   // chunk 78 (Wa2 [st][q][16][8], lower 4KB valid) — final drain
  f32x4 av = z4;
#pragma unroll
  for (int st = 0; st < 4; ++st) {
    short8 bf = *(const short8*)(C + st * 512 + q * 128 + ml * 8);
    av = __builtin_amdgcn_mfma_f32_16x16x32_bf16(a1f[st], bf, av, 0, 0, 0);
  }
  float ba2v = ba2[ml & 7];
#pragma unroll
  for (int r2 = 0; r2 < 4; ++r2) {
    float aa = av[r2] + ba2v;
    float s = aa + __shfl_xor(aa, 1); s += __shfl_xor(s, 2); s += __shfl_xor(s, 4);
    if (ml < 8)
      out[(size_t)(row0 + wv * 16 + q * 4 + r2) * 8 + ml] = aa - s * 0.125f + vbuf[wv * 16 + q * 4 + r2];
  }
}

extern "C" void kernel_launch(void* const* d_in, const int* in_sizes, int n_in,
                              void* d_out, int out_size, void* d_ws, size_t ws_size,
                              hipStream_t stream) {
  const float* o   = (const float*)d_in[0];
  const float* zm  = (const float*)d_in[1];
  const float* cp  = (const float*)d_in[2];
  const float* Wb  = (const float*)d_in[3];
  const float* bb  = (const float*)d_in[4];
  const float* Wz  = (const float*)d_in[5];
  const float* bz  = (const float*)d_in[6];
  const float* Wm  = (const float*)d_in[7];
  const float* bm  = (const float*)d_in[8];
  const float* Wg  = (const float*)d_in[9];
  const float* Wgl = (const float*)d_in[10];
  const float* Wv  = (const float*)d_in[11];
  const float* bv  = (const float*)d_in[12];
  const float* Wa1 = (const float*)d_in[13];
  const float* ba1 = (const float*)d_in[14];
  const float* Wa2 = (const float*)d_in[15];
  const float* ba2 = (const float*)d_in[16];
  unsigned short* wsT = (unsigned short*)d_ws;

  int B = in_sizes[0] / 256;  // 65536

  hipLaunchKernelGGL(prep_weights, dim3(1256), dim3(256), 0, stream,
                     Wb, Wm, Wa1, Wg, Wgl, Wa2, wsT);
  hipLaunchKernelGGL(dueling_fused, dim3(B / 128), dim3(512), 0, stream,
                     o, zm, cp, bb, Wz, bz, bm, Wv, bv, ba1, ba2,
                     wsT, (float*)d_out);
}